// Round 8
// baseline (1277.119 us; speedup 1.0000x reference)
//
#include <hip/hip_runtime.h>
#include <cstdint>
#include <cstddef>

#define NN 131072
#define EE 524288
#define GG 4096
#define NPASS 4

typedef __attribute__((ext_vector_type(4))) float f32x4;
typedef __attribute__((ext_vector_type(8))) short bfrag;

__device__ __forceinline__ unsigned short f2bf(float f) {
  union { float f; unsigned u; } v; v.f = f;
  unsigned r = v.u + 0x7fffu + ((v.u >> 16) & 1u);
  return (unsigned short)(r >> 16);
}
__device__ __forceinline__ float bf2f(unsigned short h) {
  union { unsigned u; float f; } v; v.u = ((unsigned)h) << 16;
  return v.f;
}
__device__ __forceinline__ unsigned pack2(float x, float y) {
  return (unsigned)f2bf(x) | ((unsigned)f2bf(y) << 16);
}
__device__ __forceinline__ float sigm(float x) { return 1.f / (1.f + __expf(-x)); }
// fast forms (validated R3/R4/R7 at absmax 0.5): v_exp + v_rcp, saturate at +-inf
__device__ __forceinline__ float sigm_fast(float x) {
  return __builtin_amdgcn_rcpf(1.f + __expf(-x));
}
__device__ __forceinline__ float tanh_fast(float x) {
  return 1.f - 2.f * __builtin_amdgcn_rcpf(1.f + __expf(2.f * x));
}

// async global->LDS 16B: LDS dest is wave-uniform base + lane*16
__device__ __forceinline__ void cp16(unsigned short* l, const unsigned short* g) {
  __builtin_amdgcn_global_load_lds(
      (const __attribute__((address_space(1))) unsigned int*)g,
      (__attribute__((address_space(3))) unsigned int*)l, 16, 0, 0);
}

// ---------------- weight prep ----------------
__global__ void prep_wb(const float* __restrict__ Wmsg, unsigned short* __restrict__ Wb) {
  int idx = blockIdx.x * 256 + threadIdx.x;  // 256*512
  if (idx >= 256 * 512) return;
  int m = idx >> 9, k = idx & 511;
  int t = k >> 7, d = k & 127;
  Wb[idx] = f2bf(Wmsg[((size_t)t * 256 + m) * 128 + d]);
}

// Wgru rows interleaved by gate: out-col = 4*d + g, g in {r,z,n,hn}
__global__ void prep_wgru(const float* __restrict__ Wih, const float* __restrict__ Whh,
                          unsigned short* __restrict__ Wgru) {
  int idx = blockIdx.x * 256 + threadIdx.x;  // 512*384
  if (idx >= 512 * 384) return;
  int j = idx / 384, kk = idx % 384;
  float v;
  if (kk < 256) v = (j < 384) ? Wih[j * 256 + kk] : 0.f;
  else          v = (j < 256) ? Whh[j * 128 + (kk - 256)]
                   : ((j >= 384) ? Whh[(j - 128) * 128 + (kk - 256)] : 0.f);
  int g = (j < 128) ? 0 : (j < 256) ? 1 : (j < 384) ? 2 : 3;
  int d = j & 127;
  Wgru[(size_t)(4 * d + g) * 384 + kk] = f2bf(v);
}

__global__ void prep_bias(const float* __restrict__ bih, const float* __restrict__ bhh,
                          float* __restrict__ biasg) {
  int j = blockIdx.x * 256 + threadIdx.x;
  if (j >= 512) return;
  float v;
  if (j < 256) v = bih[j] + bhh[j];
  else if (j < 384) v = bih[j];
  else v = bhh[j - 128];
  int g = (j < 128) ? 0 : (j < 256) ? 1 : (j < 384) ? 2 : 3;
  int d = j & 127;
  biasg[4 * d + g] = v;
}

// WcT[d*256 + j] = sum_k Wx[j][k] * Wn2g[k*128+d], Wx = [Wloc; Wlv] (fp32)
__global__ void compose_k(const float* __restrict__ Wloc, const float* __restrict__ Wlv,
                          const float* __restrict__ Wn2g, float* __restrict__ WcT) {
  int b = blockIdx.x;  // 128 blocks
  int jl = threadIdx.x >> 7, d = threadIdx.x & 127;
  int j = b * 2 + jl;
  const float* wx = (j < 128) ? Wloc + (size_t)j * 512 : Wlv + (size_t)(j - 128) * 512;
  float acc = 0.f;
  for (int k = 0; k < 512; k++) acc += wx[k] * Wn2g[k * 128 + d];
  WcT[d * 256 + j] = acc;
}

__global__ void cvec_k(const float* __restrict__ Wloc, const float* __restrict__ Wlv,
                       const float* __restrict__ bn2g, float* __restrict__ cvec) {
  int j = threadIdx.x;  // 256
  const float* wx = (j < 128) ? Wloc + (size_t)j * 512 : Wlv + (size_t)(j - 128) * 512;
  float a = 0.f;
  for (int k = 0; k < 512; k++) a += wx[k] * bn2g[k];
  cvec[j] = a;
}

// ---------------- init ----------------
__global__ void init_h(const int* __restrict__ nt, const float* __restrict__ emb,
                       unsigned short* __restrict__ H) {
  size_t idx = (size_t)blockIdx.x * 256 + threadIdx.x;  // N*128
  int n = (int)(idx >> 7), d = (int)(idx & 127);
  H[idx] = f2bf(emb[(size_t)nt[n] * 128 + d]);
}

// ---------------- CSR build (once per call) ----------------
__global__ void cnt4_k(const int* __restrict__ edst, const int* __restrict__ etype,
                       int* __restrict__ cnti) {
  int e = blockIdx.x * 256 + threadIdx.x;
  if (e >= EE) return;
  atomicAdd(&cnti[edst[e] * 4 + etype[e]], 1);
}

// deg[n] = sum_t cnti[n*4+t]; cnt (float) copy
__global__ void degsum_k(const int* __restrict__ cnti, int* __restrict__ deg,
                         float* __restrict__ cnt) {
  int n = blockIdx.x * 256 + threadIdx.x;
  if (n >= NN) return;
  int4 c4 = *(const int4*)&cnti[n * 4];
  deg[n] = c4.x + c4.y + c4.z + c4.w;
  float4 f4 = make_float4((float)c4.x, (float)c4.y, (float)c4.z, (float)c4.w);
  *(float4*)&cnt[n * 4] = f4;
}

// R8: int4-vectorized loads/stores (was 128 scalar loads + 256 scalar stores
// per thread on a single block = one CU).
__global__ __launch_bounds__(1024) void scan_k(const int* __restrict__ deg,
                                               int* __restrict__ rowptr,
                                               int* __restrict__ cursor) {
  __shared__ int part[1024];
  int t = threadIdx.x;
  int base = t * 128;
  const int4* deg4 = (const int4*)(deg + base);
  int s = 0;
#pragma unroll 8
  for (int i = 0; i < 32; i++) {
    int4 d = deg4[i];
    s += d.x + d.y + d.z + d.w;
  }
  part[t] = s;
  __syncthreads();
  for (int off = 1; off < 1024; off <<= 1) {
    int v = (t >= off) ? part[t - off] : 0;
    __syncthreads();
    part[t] += v;
    __syncthreads();
  }
  int run = part[t] - s;  // exclusive prefix
#pragma unroll 8
  for (int i = 0; i < 32; i++) {
    int4 d = deg4[i];
    int4 rp;
    rp.x = run; run += d.x;
    rp.y = run; run += d.y;
    rp.z = run; run += d.z;
    rp.w = run; run += d.w;
    *(int4*)&rowptr[base + i * 4] = rp;
    *(int4*)&cursor[base + i * 4] = rp;
  }
  if (t == 1023) rowptr[NN] = run;
}

__global__ void fill_k(const int* __restrict__ esrc, const int* __restrict__ edst,
                       const int* __restrict__ etype, int* __restrict__ cursor,
                       unsigned* __restrict__ epack) {
  int e = blockIdx.x * 256 + threadIdx.x;
  if (e >= EE) return;
  int pos = atomicAdd(&cursor[edst[e]], 1);
  epack[pos] = ((unsigned)etype[e] << 17) | (unsigned)esrc[e];
}

// ---------------- per-pass aggregation: s[n, t*128+d] = sum h[src] (bf16 out) ----------------
__global__ __launch_bounds__(256) void agg_k(const int* __restrict__ rowptr,
                                             const unsigned* __restrict__ epack,
                                             const unsigned short* __restrict__ H,
                                             unsigned short* __restrict__ s) {
  int n = blockIdx.x * 4 + (threadIdx.x >> 6);
  int lane = threadIdx.x & 63;
  int beg = rowptr[n], end = rowptr[n + 1];
  const unsigned short* hbase = H + lane * 2;
  float a0 = 0.f, a1 = 0.f, b0 = 0.f, b1 = 0.f;
  float c0 = 0.f, c1 = 0.f, d0 = 0.f, d1 = 0.f;
#define ACCUM(P, HV)                                              \
  {                                                               \
    int t_ = (int)((P) >> 17);                                    \
    float v0_ = bf2f((unsigned short)((HV) & 0xffffu));           \
    float v1_ = bf2f((unsigned short)((HV) >> 16));               \
    if (t_ == 0)      { a0 += v0_; a1 += v1_; }                   \
    else if (t_ == 1) { b0 += v0_; b1 += v1_; }                   \
    else if (t_ == 2) { c0 += v0_; c1 += v1_; }                   \
    else              { d0 += v0_; d1 += v1_; }                   \
  }
  for (int base = beg; base < end; base += 64) {
    int cnt = end - base;
    if (cnt > 64) cnt = 64;
    int mye = base + lane;
    unsigned ep = (mye < end) ? epack[mye] : 0u;  // coalesced pre-load
    if (cnt > 0) {
      unsigned p = (unsigned)__shfl((int)ep, 0);
      unsigned hv = *(const unsigned*)&hbase[(size_t)(p & 0x1FFFFu) * 128];
      for (int j = 1; j < cnt; j++) {
        unsigned pn = (unsigned)__shfl((int)ep, j);
        unsigned hvn = *(const unsigned*)&hbase[(size_t)(pn & 0x1FFFFu) * 128];
        ACCUM(p, hv);
        p = pn;
        hv = hvn;
      }
      ACCUM(p, hv);
    }
  }
#undef ACCUM
  unsigned short* srow = s + (size_t)n * 512;
  *(unsigned*)&srow[0 * 128 + lane * 2] = pack2(a0, a1);
  *(unsigned*)&srow[1 * 128 + lane * 2] = pack2(b0, b1);
  *(unsigned*)&srow[2 * 128 + lane * 2] = pack2(c0, c1);
  *(unsigned*)&srow[3 * 128 + lane * 2] = pack2(d0, d1);
}

// ---------------- pass GEMM 1: m = relu(s @ Wb^T + cnt*b_msg) ----------------
// R2-verified geometry + R5 counted-vmcnt pipeline. NEW (R8): LDS-staged
// coalesced m-write — counters showed WRITE_SIZE 122 MB for a 67 MB store
// (2-B scattered stores into stride-1KB rows -> partial-sector write
// amplification). Epilogue now stages each 64-row chunk (32 KB, overlaid on
// the dead As/Bs) and sweeps it out with 16-B coalesced stores.
__global__ __launch_bounds__(512, 4) void msgemm_k(
    unsigned short* __restrict__ s, const float* __restrict__ cnt,
    const unsigned short* __restrict__ Wb, const float* __restrict__ bmsg) {
  __shared__ __align__(16) unsigned char smem[49152];
  unsigned short* As = (unsigned short*)smem;             // [2][128*32], 16 KB
  unsigned short* Bs = (unsigned short*)(smem + 16384);   // [2][256*32], 32 KB
  unsigned short* mst = (unsigned short*)smem;            // epilogue [64][256]
  int i0 = blockIdx.x * 128;
  int tid = threadIdx.x, lane = tid & 63, w = tid >> 6;
  int wi = w >> 1, wj = w & 1;
  int q = lane >> 4, r = lane & 15;
  int srow = tid >> 2;                                   // staged row (0..127)
  int swcol = ((tid & 3) ^ ((srow >> 1) & 3)) * 8;       // inverse-swizzled col

  const unsigned short* sP = s + (size_t)(i0 + srow) * 512 + swcol;
  const unsigned short* WbP = Wb + (size_t)srow * 512 + swcol;

  // swizzled read offsets (elements)
  int aoff[2], boff[8];
#pragma unroll
  for (int rt = 0; rt < 2; rt++) {
    int row = wi * 32 + rt * 16 + r;
    aoff[rt] = row * 32 + (q ^ ((row >> 1) & 3)) * 8;
  }
#pragma unroll
  for (int ct = 0; ct < 8; ct++) {
    int row = wj * 128 + ct * 16 + r;
    boff[ct] = row * 32 + (q ^ ((row >> 1) & 3)) * 8;
  }

  f32x4 acc[2][8];
#pragma unroll
  for (int a = 0; a < 2; a++)
#pragma unroll
    for (int b = 0; b < 8; b++) acc[a][b] = f32x4{0.f, 0.f, 0.f, 0.f};

  // pre-stage ks=0 (no barrier: first in-loop vmcnt+B1 publishes it)
  cp16(&As[0 * 4096 + w * 512], sP);
#pragma unroll
  for (int c = 0; c < 2; c++)
    cp16(&Bs[0 * 8192 + c * 4096 + w * 512], WbP + (size_t)(c * 128) * 512);

  for (int ks = 0; ks < 16; ks++) {
    int b = ks & 1;
    if (ks < 15) {
      int nb = b ^ 1;
      cp16(&As[nb * 4096 + w * 512], sP + (ks + 1) * 32);
#pragma unroll
      for (int c = 0; c < 2; c++)
        cp16(&Bs[nb * 8192 + c * 4096 + w * 512],
             WbP + (size_t)(c * 128) * 512 + (ks + 1) * 32);
      asm volatile("s_waitcnt vmcnt(3)" ::: "memory");  // window ks's loads landed
    } else {
      asm volatile("s_waitcnt vmcnt(0)" ::: "memory");
    }
    __builtin_amdgcn_s_barrier();        // B1: buf b ready for all waves
    __builtin_amdgcn_sched_barrier(0);
    bfrag af[2];
#pragma unroll
    for (int rt = 0; rt < 2; rt++) af[rt] = *(const bfrag*)&As[b * 4096 + aoff[rt]];
#pragma unroll
    for (int ct = 0; ct < 8; ct++) {
      bfrag bfr = *(const bfrag*)&Bs[b * 8192 + boff[ct]];
#pragma unroll
      for (int rt = 0; rt < 2; rt++)
        acc[rt][ct] =
            __builtin_amdgcn_mfma_f32_16x16x32_bf16(af[rt], bfr, acc[rt][ct], 0, 0, 0);
    }
    __builtin_amdgcn_sched_barrier(0);
    __builtin_amdgcn_s_barrier();        // B2: all reads of buf b done
    __builtin_amdgcn_sched_barrier(0);
  }

  // ---- epilogue: + cnt*b_msg, relu; LDS-staged coalesced write ----
  // chunk c covers rows [c*64, c*64+64); thread's rows all live in chunk wi>>1.
  int mychunk = wi >> 1;
#pragma unroll
  for (int chunk = 0; chunk < 2; chunk++) {
    if (mychunk == chunk) {
#pragma unroll
      for (int ct = 0; ct < 8; ct++) {
        int j = wj * 128 + ct * 16 + r;
        float b0 = bmsg[j], b1 = bmsg[256 + j], b2 = bmsg[512 + j], b3 = bmsg[768 + j];
#pragma unroll
        for (int rt = 0; rt < 2; rt++) {
#pragma unroll
          for (int reg = 0; reg < 4; reg++) {
            int il = wi * 32 + rt * 16 + q * 4 + reg;
            float4 c4 = *(const float4*)&cnt[(size_t)(i0 + il) * 4];
            float v = acc[rt][ct][reg] + c4.x * b0 + c4.y * b1 + c4.z * b2 + c4.w * b3;
            v = v > 0.f ? v : 0.f;
            mst[(il - chunk * 64) * 256 + j] = f2bf(v);
          }
        }
      }
    }
    __syncthreads();
    // coalesced sweep: 8 threads/row x 64 B (32 elems) each
    {
      int row = tid >> 3;
      int off = (tid & 7) * 32;
      size_t g = (size_t)(i0 + chunk * 64 + row) * 512 + off;
#pragma unroll
      for (int u = 0; u < 4; u++)
        *(bfrag*)&s[g + u * 8] = *(const bfrag*)&mst[row * 256 + off + u * 8];
    }
    if (chunk == 0) __syncthreads();  // protect mst before chunk-1 overwrite
  }
}

// ---------------- pass GEMM 2: gates = [m | H] @ Wgru^T, GRU epilogue -> Hn ----
// R6 structure (coalesced LDS-staged epilogue) + R7 fast transcendentals.
__global__ __launch_bounds__(512, 4) void grugemm_k(
    const unsigned short* __restrict__ m,   // = s, stride 512, cols [0,256)
    const unsigned short* __restrict__ Hc, unsigned short* __restrict__ Hn,
    const unsigned short* __restrict__ Wgru, const float* __restrict__ biasg) {
  __shared__ __align__(16) unsigned char smem[49152];
  unsigned short* As = (unsigned short*)smem;             // [2][128*32], 16 KB
  unsigned short* Bs = (unsigned short*)(smem + 16384);   // [2][256*32], 32 KB
  unsigned* pg = (unsigned*)smem;                         // epilogue [128][66]
  // grid = 2048; bijective XCD chunking: wg = (bid%8)*256 + bid/8
  int wg = (blockIdx.x & 7) * 256 + (blockIdx.x >> 3);
  int bcol = wg & 1;
  int i0 = (wg >> 1) * 128;
  int tid = threadIdx.x, lane = tid & 63, w = tid >> 6;
  int wi = w >> 1, wj = w & 1;
  int q = lane >> 4, r = lane & 15;
  int srow = tid >> 2;
  int swcol = ((tid & 3) ^ ((srow >> 1) & 3)) * 8;

  const unsigned short* mP = m + (size_t)(i0 + srow) * 512 + swcol;
  const unsigned short* hP = Hc + (size_t)(i0 + srow) * 128 + swcol;
  const unsigned short* WgP = Wgru + (size_t)(bcol * 256 + srow) * 384 + swcol;

  int aoff[2], boff[8];
#pragma unroll
  for (int rt = 0; rt < 2; rt++) {
    int row = wi * 32 + rt * 16 + r;
    aoff[rt] = row * 32 + (q ^ ((row >> 1) & 3)) * 8;
  }
#pragma unroll
  for (int ct = 0; ct < 8; ct++) {
    int row = wj * 128 + ct * 16 + r;
    boff[ct] = row * 32 + (q ^ ((row >> 1) & 3)) * 8;
  }

  f32x4 acc[2][8];
#pragma unroll
  for (int a = 0; a < 2; a++)
#pragma unroll
    for (int b = 0; b < 8; b++) acc[a][b] = f32x4{0.f, 0.f, 0.f, 0.f};

  // pre-stage ks=0 (m part; no barrier)
  cp16(&As[0 * 4096 + w * 512], mP);
#pragma unroll
  for (int c = 0; c < 2; c++)
    cp16(&Bs[0 * 8192 + c * 4096 + w * 512], WgP + (size_t)(c * 128) * 384);

  for (int ks = 0; ks < 12; ks++) {
    int b = ks & 1;
    if (ks < 11) {
      int nb = b ^ 1;
      int nks = ks + 1;
      const unsigned short* aSrc =
          (nks < 8) ? (mP + nks * 32) : (hP + (nks - 8) * 32);
      cp16(&As[nb * 4096 + w * 512], aSrc);
#pragma unroll
      for (int c = 0; c < 2; c++)
        cp16(&Bs[nb * 8192 + c * 4096 + w * 512],
             WgP + (size_t)(c * 128) * 384 + nks * 32);
      asm volatile("s_waitcnt vmcnt(3)" ::: "memory");
    } else {
      asm volatile("s_waitcnt vmcnt(0)" ::: "memory");
    }
    __builtin_amdgcn_s_barrier();        // B1
    __builtin_amdgcn_sched_barrier(0);
    bfrag af[2];
#pragma unroll
    for (int rt = 0; rt < 2; rt++) af[rt] = *(const bfrag*)&As[b * 4096 + aoff[rt]];
#pragma unroll
    for (int ct = 0; ct < 8; ct++) {
      bfrag bfr = *(const bfrag*)&Bs[b * 8192 + boff[ct]];
#pragma unroll
      for (int rt = 0; rt < 2; rt++)
        acc[rt][ct] =
            __builtin_amdgcn_mfma_f32_16x16x32_bf16(af[rt], bfr, acc[rt][ct], 0, 0, 0);
    }
    __builtin_amdgcn_sched_barrier(0);
    __builtin_amdgcn_s_barrier();        // B2
    __builtin_amdgcn_sched_barrier(0);
  }

  // ---- epilogue phase 1: gates -> pg[il][dl] = pack2((1-z)*n, z) ----
  int rr = r & 3;
  bool s1 = (lane & 1) != 0, s2 = (lane & 2) != 0;
#pragma unroll
  for (int ct = 0; ct < 8; ct++) {
    float bias = biasg[bcol * 256 + wj * 128 + ct * 16 + r];
    int dl = wj * 32 + ct * 4 + (r >> 2);   // local d in [0,64)
#pragma unroll
    for (int rt = 0; rt < 2; rt++) {
      float v0 = acc[rt][ct][0] + bias;
      float v1 = acc[rt][ct][1] + bias;
      float v2 = acc[rt][ct][2] + bias;
      float v3 = acc[rt][ct][3] + bias;
      float t, rcv;
      t = s1 ? v0 : v1; rcv = __shfl_xor(t, 1);
      v0 = s1 ? rcv : v0; v1 = s1 ? v1 : rcv;
      t = s1 ? v2 : v3; rcv = __shfl_xor(t, 1);
      v2 = s1 ? rcv : v2; v3 = s1 ? v3 : rcv;
      t = s2 ? v0 : v2; rcv = __shfl_xor(t, 2);
      v0 = s2 ? rcv : v0; v2 = s2 ? v2 : rcv;
      t = s2 ? v1 : v3; rcv = __shfl_xor(t, 2);
      v1 = s2 ? rcv : v1; v3 = s2 ? v3 : rcv;
      int il = wi * 32 + rt * 16 + q * 4 + rr;
      float rg = sigm_fast(v0), zg = sigm_fast(v1);
      float ng = tanh_fast(v2 + rg * v3);
      pg[il * 66 + dl] = pack2((1.f - zg) * ng, zg);
    }
  }
  __syncthreads();

  // ---- epilogue phase 2: coalesced blend + store ----
#pragma unroll
  for (int half = 0; half < 2; half++) {
    int row = half * 64 + (tid >> 3);
    int c0 = (tid & 7) * 8;
    size_t gbase = (size_t)(i0 + row) * 128 + bcol * 64 + c0;
    bfrag hv8 = *(const bfrag*)&Hc[gbase];
    uint4 p0 = *(const uint4*)&pg[row * 66 + c0];
    uint4 p1 = *(const uint4*)&pg[row * 66 + c0 + 4];
    unsigned pw[8] = {p0.x, p0.y, p0.z, p0.w, p1.x, p1.y, p1.z, p1.w};
    bfrag outv;
#pragma unroll
    for (int e = 0; e < 8; e++) {
      float a = bf2f((unsigned short)(pw[e] & 0xffffu));
      float z = bf2f((unsigned short)(pw[e] >> 16));
      float hold = bf2f((unsigned short)hv8[e]);
      outv[e] = (short)f2bf(a + z * hold);
    }
    *(bfrag*)&Hn[gbase] = outv;
  }
}

// ---------------- readout ----------------
__global__ __launch_bounds__(256) void gate_k(const unsigned short* __restrict__ H,
                                              const float* __restrict__ Wg,
                                              const float* __restrict__ bg,
                                              float* __restrict__ gate) {
  __shared__ float wg[128];
  if (threadIdx.x < 128) wg[threadIdx.x] = Wg[threadIdx.x];
  __syncthreads();
  int g = threadIdx.x >> 4, sub = threadIdx.x & 15;
  int n = blockIdx.x * 16 + g;
  const unsigned short* hr = H + (size_t)n * 128;
  float p = 0.f;
  for (int k = sub; k < 128; k += 16) p += bf2f(hr[k]) * wg[k];
  p += __shfl_xor(p, 1);
  p += __shfl_xor(p, 2);
  p += __shfl_xor(p, 4);
  p += __shfl_xor(p, 8);
  if (sub == 0) gate[n] = sigm(p + bg[0]);
}

// per-graph: gsum[g] = sum gate_n * h_n (fp32), sg[g] = sum gate_n
__global__ __launch_bounds__(256) void gsum_k(const unsigned short* __restrict__ H,
                                              const float* __restrict__ gate,
                                              const int* __restrict__ ptr,
                                              float* __restrict__ gsum,
                                              float* __restrict__ sg) {
  int g = blockIdx.x * 4 + (threadIdx.x >> 6);
  int lane = threadIdx.x & 63;
  int start = ptr[g], end = ptr[g + 1];
  float a0 = 0.f, a1 = 0.f, gs = 0.f;
  for (int n = start; n < end; n++) {
    float gt = gate[n];
    unsigned hv = *(const unsigned*)&H[(size_t)n * 128 + lane * 2];
    a0 += gt * bf2f((unsigned short)(hv & 0xffffu));
    a1 += gt * bf2f((unsigned short)(hv >> 16));
    gs += gt;
  }
  gsum[(size_t)g * 128 + lane * 2] = a0;
  gsum[(size_t)g * 128 + lane * 2 + 1] = a1;
  if (lane == 0) sg[g] = gs;
}

// z[j] = gsum[g] . WcT[:,j] + sg[g]*cvec[j] + bias[j]
__global__ __launch_bounds__(256) void zfinal_k(const float* __restrict__ gsum,
                                                const float* __restrict__ sg,
                                                const float* __restrict__ WcT,
                                                const float* __restrict__ cvec,
                                                const float* __restrict__ bloc,
                                                const float* __restrict__ blv,
                                                float* __restrict__ out) {
  __shared__ float gs[128];
  __shared__ float sgs;
  int g = blockIdx.x;
  int j = threadIdx.x;
  if (j < 128) gs[j] = gsum[(size_t)g * 128 + j];
  if (j == 0) sgs = sg[g];
  __syncthreads();
  float acc = (j < 128 ? bloc[j] : blv[j - 128]) + sgs * cvec[j];
  for (int d = 0; d < 128; d++) acc += gs[d] * WcT[d * 256 + j];
  size_t o = (j < 128) ? ((size_t)g * 128 + j)
                       : ((size_t)GG * 128 + (size_t)g * 128 + (j - 128));
  out[o] = acc;
}

extern "C" void kernel_launch(void* const* d_in, const int* in_sizes, int n_in,
                              void* d_out, int out_size, void* d_ws, size_t ws_size,
                              hipStream_t stream) {
  const int* node_types = (const int*)d_in[0];
  const int* esrc = (const int*)d_in[1];
  const int* edst = (const int*)d_in[2];
  const int* etype = (const int*)d_in[3];
  const int* ptr = (const int*)d_in[4];
  const float* emb = (const float*)d_in[5];
  const float* Wmsg = (const float*)d_in[6];
  const float* bmsg = (const float*)d_in[7];
  const float* Wih = (const float*)d_in[8];
  const float* Whh = (const float*)d_in[9];
  const float* bih = (const float*)d_in[10];
  const float* bhh = (const float*)d_in[11];
  const float* Wg = (const float*)d_in[12];
  const float* bg = (const float*)d_in[13];
  const float* Wn2g = (const float*)d_in[14];
  const float* bn2g = (const float*)d_in[15];
  const float* Wloc = (const float*)d_in[16];
  const float* bloc = (const float*)d_in[17];
  const float* Wlv = (const float*)d_in[18];
  const float* blv = (const float*)d_in[19];
  float* out = (float*)d_out;

  char* ws = (char*)d_ws;
  size_t off = 0;
  unsigned short* s = (unsigned short*)(ws);  // N x 512 bf16; cols [0,256) reused as m
  off += (size_t)NN * 512 * 2;
  unsigned short* H0 = (unsigned short*)(ws + off);  // N x 128 bf16
  off += (size_t)NN * 128 * 2;
  unsigned short* H1 = (unsigned short*)(ws + off);
  off += (size_t)NN * 128 * 2;
  float* cnt = (float*)(ws + off);
  off += (size_t)NN * 4 * 4;
  int* cnti = (int*)(ws + off);
  off += (size_t)NN * 4 * 4;
  int* deg = (int*)(ws + off);
  off += (size_t)NN * 4;
  int* rowptr = (int*)(ws + off);
  off += (size_t)(NN + 64) * 4;
  int* cursor = (int*)(ws + off);
  off += (size_t)NN * 4;
  unsigned* epack = (unsigned*)(ws + off);
  off += (size_t)EE * 4;
  float* gate = (float*)(ws + off);
  off += (size_t)NN * 4;
  float* gsum = (float*)(ws + off);
  off += (size_t)GG * 128 * 4;
  float* sg = (float*)(ws + off);
  off += (size_t)GG * 4;
  float* WcT = (float*)(ws + off);
  off += 128 * 256 * 4;
  float* cvec = (float*)(ws + off);
  off += 256 * 4;
  unsigned short* Wb = (unsigned short*)(ws + off);
  off += 256 * 512 * 2;
  unsigned short* Wgru = (unsigned short*)(ws + off);
  off += 512 * 384 * 2;
  float* biasg = (float*)(ws + off);
  off += 512 * 4;
  // total ~214 MB < 256 MiB ws

  hipMemsetAsync(cnti, 0, (size_t)NN * 16, stream);
  prep_wb<<<512, 256, 0, stream>>>(Wmsg, Wb);
  prep_wgru<<<768, 256, 0, stream>>>(Wih, Whh, Wgru);
  prep_bias<<<2, 256, 0, stream>>>(bih, bhh, biasg);
  compose_k<<<128, 256, 0, stream>>>(Wloc, Wlv, Wn2g, WcT);
  cvec_k<<<1, 256, 0, stream>>>(Wloc, Wlv, bn2g, cvec);
  init_h<<<NN * 128 / 256, 256, 0, stream>>>(node_types, emb, H0);
  cnt4_k<<<EE / 256, 256, 0, stream>>>(edst, etype, cnti);
  degsum_k<<<NN / 256, 256, 0, stream>>>(cnti, deg, cnt);
  scan_k<<<1, 1024, 0, stream>>>(deg, rowptr, cursor);
  fill_k<<<EE / 256, 256, 0, stream>>>(esrc, edst, etype, cursor, epack);

  unsigned short* Hc = H0;
  unsigned short* Hn = H1;
  for (int p = 0; p < NPASS; p++) {
    agg_k<<<NN / 4, 256, 0, stream>>>(rowptr, epack, Hc, s);
    msgemm_k<<<NN / 128, 512, 0, stream>>>(s, cnt, Wb, bmsg);
    grugemm_k<<<NN / 128 * 2, 512, 0, stream>>>(s, Hc, Hn, Wgru, biasg);
    unsigned short* tmp = Hc; Hc = Hn; Hn = tmp;
  }

  gate_k<<<NN / 16, 256, 0, stream>>>(Hc, Wg, bg, gate);
  gsum_k<<<GG / 4, 256, 0, stream>>>(Hc, gate, ptr, gsum, sg);
  zfinal_k<<<GG, 256, 0, stream>>>(gsum, sg, WcT, cvec, bloc, blv, out);
}

// Round 9
// 1166.936 us; speedup vs baseline: 1.0944x; 1.0944x over previous
//
#include <hip/hip_runtime.h>
#include <cstdint>
#include <cstddef>

#define NN 131072
#define EE 524288
#define GG 4096
#define NPASS 4

typedef __attribute__((ext_vector_type(4))) float f32x4;
typedef __attribute__((ext_vector_type(8))) short bfrag;

__device__ __forceinline__ unsigned short f2bf(float f) {
  union { float f; unsigned u; } v; v.f = f;
  unsigned r = v.u + 0x7fffu + ((v.u >> 16) & 1u);
  return (unsigned short)(r >> 16);
}
__device__ __forceinline__ float bf2f(unsigned short h) {
  union { unsigned u; float f; } v; v.u = ((unsigned)h) << 16;
  return v.f;
}
__device__ __forceinline__ unsigned pack2(float x, float y) {
  return (unsigned)f2bf(x) | ((unsigned)f2bf(y) << 16);
}
__device__ __forceinline__ float sigm(float x) { return 1.f / (1.f + __expf(-x)); }
// fast forms (validated R3/R4/R7 at absmax 0.5): v_exp + v_rcp, saturate at +-inf
__device__ __forceinline__ float sigm_fast(float x) {
  return __builtin_amdgcn_rcpf(1.f + __expf(-x));
}
__device__ __forceinline__ float tanh_fast(float x) {
  return 1.f - 2.f * __builtin_amdgcn_rcpf(1.f + __expf(2.f * x));
}

// async global->LDS 16B: LDS dest is wave-uniform base + lane*16
__device__ __forceinline__ void cp16(unsigned short* l, const unsigned short* g) {
  __builtin_amdgcn_global_load_lds(
      (const __attribute__((address_space(1))) unsigned int*)g,
      (__attribute__((address_space(3))) unsigned int*)l, 16, 0, 0);
}

// ---------------- weight prep ----------------
__global__ void prep_wb(const float* __restrict__ Wmsg, unsigned short* __restrict__ Wb) {
  int idx = blockIdx.x * 256 + threadIdx.x;  // 256*512
  if (idx >= 256 * 512) return;
  int m = idx >> 9, k = idx & 511;
  int t = k >> 7, d = k & 127;
  Wb[idx] = f2bf(Wmsg[((size_t)t * 256 + m) * 128 + d]);
}

// Wgru rows interleaved by gate: out-col = 4*d + g, g in {r,z,n,hn}
__global__ void prep_wgru(const float* __restrict__ Wih, const float* __restrict__ Whh,
                          unsigned short* __restrict__ Wgru) {
  int idx = blockIdx.x * 256 + threadIdx.x;  // 512*384
  if (idx >= 512 * 384) return;
  int j = idx / 384, kk = idx % 384;
  float v;
  if (kk < 256) v = (j < 384) ? Wih[j * 256 + kk] : 0.f;
  else          v = (j < 256) ? Whh[j * 128 + (kk - 256)]
                   : ((j >= 384) ? Whh[(j - 128) * 128 + (kk - 256)] : 0.f);
  int g = (j < 128) ? 0 : (j < 256) ? 1 : (j < 384) ? 2 : 3;
  int d = j & 127;
  Wgru[(size_t)(4 * d + g) * 384 + kk] = f2bf(v);
}

__global__ void prep_bias(const float* __restrict__ bih, const float* __restrict__ bhh,
                          float* __restrict__ biasg) {
  int j = blockIdx.x * 256 + threadIdx.x;
  if (j >= 512) return;
  float v;
  if (j < 256) v = bih[j] + bhh[j];
  else if (j < 384) v = bih[j];
  else v = bhh[j - 128];
  int g = (j < 128) ? 0 : (j < 256) ? 1 : (j < 384) ? 2 : 3;
  int d = j & 127;
  biasg[4 * d + g] = v;
}

// WcT[d*256 + j] = sum_k Wx[j][k] * Wn2g[k*128+d], Wx = [Wloc; Wlv] (fp32)
__global__ void compose_k(const float* __restrict__ Wloc, const float* __restrict__ Wlv,
                          const float* __restrict__ Wn2g, float* __restrict__ WcT) {
  int b = blockIdx.x;  // 128 blocks
  int jl = threadIdx.x >> 7, d = threadIdx.x & 127;
  int j = b * 2 + jl;
  const float* wx = (j < 128) ? Wloc + (size_t)j * 512 : Wlv + (size_t)(j - 128) * 512;
  float acc = 0.f;
  for (int k = 0; k < 512; k++) acc += wx[k] * Wn2g[k * 128 + d];
  WcT[d * 256 + j] = acc;
}

__global__ void cvec_k(const float* __restrict__ Wloc, const float* __restrict__ Wlv,
                       const float* __restrict__ bn2g, float* __restrict__ cvec) {
  int j = threadIdx.x;  // 256
  const float* wx = (j < 128) ? Wloc + (size_t)j * 512 : Wlv + (size_t)(j - 128) * 512;
  float a = 0.f;
  for (int k = 0; k < 512; k++) a += wx[k] * bn2g[k];
  cvec[j] = a;
}

// ---------------- init ----------------
__global__ void init_h(const int* __restrict__ nt, const float* __restrict__ emb,
                       unsigned short* __restrict__ H) {
  size_t idx = (size_t)blockIdx.x * 256 + threadIdx.x;  // N*128
  int n = (int)(idx >> 7), d = (int)(idx & 127);
  H[idx] = f2bf(emb[(size_t)nt[n] * 128 + d]);
}

// ---------------- CSR build (once per call) ----------------
__global__ void cnt4_k(const int* __restrict__ edst, const int* __restrict__ etype,
                       int* __restrict__ cnti) {
  int e = blockIdx.x * 256 + threadIdx.x;
  if (e >= EE) return;
  atomicAdd(&cnti[edst[e] * 4 + etype[e]], 1);
}

// deg[n] = sum_t cnti[n*4+t]; cnt (float) copy
__global__ void degsum_k(const int* __restrict__ cnti, int* __restrict__ deg,
                         float* __restrict__ cnt) {
  int n = blockIdx.x * 256 + threadIdx.x;
  if (n >= NN) return;
  int4 c4 = *(const int4*)&cnti[n * 4];
  deg[n] = c4.x + c4.y + c4.z + c4.w;
  float4 f4 = make_float4((float)c4.x, (float)c4.y, (float)c4.z, (float)c4.w);
  *(float4*)&cnt[n * 4] = f4;
}

// R8-kept: int4-vectorized loads/stores (single-block kernel).
__global__ __launch_bounds__(1024) void scan_k(const int* __restrict__ deg,
                                               int* __restrict__ rowptr,
                                               int* __restrict__ cursor) {
  __shared__ int part[1024];
  int t = threadIdx.x;
  int base = t * 128;
  const int4* deg4 = (const int4*)(deg + base);
  int s = 0;
#pragma unroll 8
  for (int i = 0; i < 32; i++) {
    int4 d = deg4[i];
    s += d.x + d.y + d.z + d.w;
  }
  part[t] = s;
  __syncthreads();
  for (int off = 1; off < 1024; off <<= 1) {
    int v = (t >= off) ? part[t - off] : 0;
    __syncthreads();
    part[t] += v;
    __syncthreads();
  }
  int run = part[t] - s;  // exclusive prefix
#pragma unroll 8
  for (int i = 0; i < 32; i++) {
    int4 d = deg4[i];
    int4 rp;
    rp.x = run; run += d.x;
    rp.y = run; run += d.y;
    rp.z = run; run += d.z;
    rp.w = run; run += d.w;
    *(int4*)&rowptr[base + i * 4] = rp;
    *(int4*)&cursor[base + i * 4] = rp;
  }
  if (t == 1023) rowptr[NN] = run;
}

__global__ void fill_k(const int* __restrict__ esrc, const int* __restrict__ edst,
                       const int* __restrict__ etype, int* __restrict__ cursor,
                       unsigned* __restrict__ epack) {
  int e = blockIdx.x * 256 + threadIdx.x;
  if (e >= EE) return;
  int pos = atomicAdd(&cursor[edst[e]], 1);
  epack[pos] = ((unsigned)etype[e] << 17) | (unsigned)esrc[e];
}

// ---------------- per-pass aggregation: s[n, t*128+d] = sum h[src] (bf16 out) ----------------
__global__ __launch_bounds__(256) void agg_k(const int* __restrict__ rowptr,
                                             const unsigned* __restrict__ epack,
                                             const unsigned short* __restrict__ H,
                                             unsigned short* __restrict__ s) {
  int n = blockIdx.x * 4 + (threadIdx.x >> 6);
  int lane = threadIdx.x & 63;
  int beg = rowptr[n], end = rowptr[n + 1];
  const unsigned short* hbase = H + lane * 2;
  float a0 = 0.f, a1 = 0.f, b0 = 0.f, b1 = 0.f;
  float c0 = 0.f, c1 = 0.f, d0 = 0.f, d1 = 0.f;
#define ACCUM(P, HV)                                              \
  {                                                               \
    int t_ = (int)((P) >> 17);                                    \
    float v0_ = bf2f((unsigned short)((HV) & 0xffffu));           \
    float v1_ = bf2f((unsigned short)((HV) >> 16));               \
    if (t_ == 0)      { a0 += v0_; a1 += v1_; }                   \
    else if (t_ == 1) { b0 += v0_; b1 += v1_; }                   \
    else if (t_ == 2) { c0 += v0_; c1 += v1_; }                   \
    else              { d0 += v0_; d1 += v1_; }                   \
  }
  for (int base = beg; base < end; base += 64) {
    int cnt = end - base;
    if (cnt > 64) cnt = 64;
    int mye = base + lane;
    unsigned ep = (mye < end) ? epack[mye] : 0u;  // coalesced pre-load
    if (cnt > 0) {
      unsigned p = (unsigned)__shfl((int)ep, 0);
      unsigned hv = *(const unsigned*)&hbase[(size_t)(p & 0x1FFFFu) * 128];
      for (int j = 1; j < cnt; j++) {
        unsigned pn = (unsigned)__shfl((int)ep, j);
        unsigned hvn = *(const unsigned*)&hbase[(size_t)(pn & 0x1FFFFu) * 128];
        ACCUM(p, hv);
        p = pn;
        hv = hvn;
      }
      ACCUM(p, hv);
    }
  }
#undef ACCUM
  unsigned short* srow = s + (size_t)n * 512;
  *(unsigned*)&srow[0 * 128 + lane * 2] = pack2(a0, a1);
  *(unsigned*)&srow[1 * 128 + lane * 2] = pack2(b0, b1);
  *(unsigned*)&srow[2 * 128 + lane * 2] = pack2(c0, c1);
  *(unsigned*)&srow[3 * 128 + lane * 2] = pack2(d0, d1);
}

// ---------------- pass GEMM 1: m = relu(s @ Wb^T + cnt*b_msg) ----------------
// R7-EXACT (measured 87.6 us): R2 geometry + R5 counted-vmcnt pipeline +
// scattered epilogue stores. R8's LDS-staged write REGRESSED (+15 us:
// WRITE_SIZE unchanged -> amplification theory falsified; added bank
// conflicts + serialization) — reverted.
__global__ __launch_bounds__(512, 4) void msgemm_k(
    unsigned short* __restrict__ s, const float* __restrict__ cnt,
    const unsigned short* __restrict__ Wb, const float* __restrict__ bmsg) {
  __shared__ __align__(16) unsigned short As[2][128 * 32];   // 16 KB
  __shared__ __align__(16) unsigned short Bs[2][256 * 32];   // 32 KB
  int i0 = blockIdx.x * 128;
  int tid = threadIdx.x, lane = tid & 63, w = tid >> 6;
  int wi = w >> 1, wj = w & 1;
  int q = lane >> 4, r = lane & 15;
  int srow = tid >> 2;                                   // staged row (0..127)
  int swcol = ((tid & 3) ^ ((srow >> 1) & 3)) * 8;       // inverse-swizzled col

  const unsigned short* sP = s + (size_t)(i0 + srow) * 512 + swcol;
  const unsigned short* WbP = Wb + (size_t)srow * 512 + swcol;

  // swizzled read offsets (elements)
  int aoff[2], boff[8];
#pragma unroll
  for (int rt = 0; rt < 2; rt++) {
    int row = wi * 32 + rt * 16 + r;
    aoff[rt] = row * 32 + (q ^ ((row >> 1) & 3)) * 8;
  }
#pragma unroll
  for (int ct = 0; ct < 8; ct++) {
    int row = wj * 128 + ct * 16 + r;
    boff[ct] = row * 32 + (q ^ ((row >> 1) & 3)) * 8;
  }

  f32x4 acc[2][8];
#pragma unroll
  for (int a = 0; a < 2; a++)
#pragma unroll
    for (int b = 0; b < 8; b++) acc[a][b] = f32x4{0.f, 0.f, 0.f, 0.f};

  // pre-stage ks=0 (no barrier: first in-loop vmcnt+B1 publishes it)
  cp16(&As[0][w * 512], sP);
#pragma unroll
  for (int c = 0; c < 2; c++)
    cp16(&Bs[0][c * 4096 + w * 512], WbP + (size_t)(c * 128) * 512);

  for (int ks = 0; ks < 16; ks++) {
    int b = ks & 1;
    if (ks < 15) {
      int nb = b ^ 1;
      cp16(&As[nb][w * 512], sP + (ks + 1) * 32);
#pragma unroll
      for (int c = 0; c < 2; c++)
        cp16(&Bs[nb][c * 4096 + w * 512],
             WbP + (size_t)(c * 128) * 512 + (ks + 1) * 32);
      asm volatile("s_waitcnt vmcnt(3)" ::: "memory");  // window ks's loads landed
    } else {
      asm volatile("s_waitcnt vmcnt(0)" ::: "memory");
    }
    __builtin_amdgcn_s_barrier();        // B1: buf b ready for all waves
    __builtin_amdgcn_sched_barrier(0);
    bfrag af[2];
#pragma unroll
    for (int rt = 0; rt < 2; rt++) af[rt] = *(const bfrag*)&As[b][aoff[rt]];
#pragma unroll
    for (int ct = 0; ct < 8; ct++) {
      bfrag bfr = *(const bfrag*)&Bs[b][boff[ct]];
#pragma unroll
      for (int rt = 0; rt < 2; rt++)
        acc[rt][ct] =
            __builtin_amdgcn_mfma_f32_16x16x32_bf16(af[rt], bfr, acc[rt][ct], 0, 0, 0);
    }
    __builtin_amdgcn_sched_barrier(0);
    __builtin_amdgcn_s_barrier();        // B2: all reads of buf b done
    __builtin_amdgcn_sched_barrier(0);
  }

  // epilogue: + cnt*b_msg, relu -> m (= s cols [0,256), stride 512)
#pragma unroll
  for (int ct = 0; ct < 8; ct++) {
    int j = wj * 128 + ct * 16 + r;
    float b0 = bmsg[j], b1 = bmsg[256 + j], b2 = bmsg[512 + j], b3 = bmsg[768 + j];
#pragma unroll
    for (int rt = 0; rt < 2; rt++) {
#pragma unroll
      for (int reg = 0; reg < 4; reg++) {
        int il = wi * 32 + rt * 16 + q * 4 + reg;
        float4 c4 = *(const float4*)&cnt[(size_t)(i0 + il) * 4];
        float v = acc[rt][ct][reg] + c4.x * b0 + c4.y * b1 + c4.z * b2 + c4.w * b3;
        v = v > 0.f ? v : 0.f;
        s[(size_t)(i0 + il) * 512 + j] = f2bf(v);
      }
    }
  }
}

// ---------------- pass GEMM 2: gates = [m | H] @ Wgru^T, GRU epilogue -> Hn ----
// R6 structure (coalesced LDS-staged epilogue) + R7 fast transcendentals.
__global__ __launch_bounds__(512, 4) void grugemm_k(
    const unsigned short* __restrict__ m,   // = s, stride 512, cols [0,256)
    const unsigned short* __restrict__ Hc, unsigned short* __restrict__ Hn,
    const unsigned short* __restrict__ Wgru, const float* __restrict__ biasg) {
  __shared__ __align__(16) unsigned char smem[49152];
  unsigned short* As = (unsigned short*)smem;             // [2][128*32], 16 KB
  unsigned short* Bs = (unsigned short*)(smem + 16384);   // [2][256*32], 32 KB
  unsigned* pg = (unsigned*)smem;                         // epilogue [128][66]
  // grid = 2048; bijective XCD chunking: wg = (bid%8)*256 + bid/8
  int wg = (blockIdx.x & 7) * 256 + (blockIdx.x >> 3);
  int bcol = wg & 1;
  int i0 = (wg >> 1) * 128;
  int tid = threadIdx.x, lane = tid & 63, w = tid >> 6;
  int wi = w >> 1, wj = w & 1;
  int q = lane >> 4, r = lane & 15;
  int srow = tid >> 2;
  int swcol = ((tid & 3) ^ ((srow >> 1) & 3)) * 8;

  const unsigned short* mP = m + (size_t)(i0 + srow) * 512 + swcol;
  const unsigned short* hP = Hc + (size_t)(i0 + srow) * 128 + swcol;
  const unsigned short* WgP = Wgru + (size_t)(bcol * 256 + srow) * 384 + swcol;

  int aoff[2], boff[8];
#pragma unroll
  for (int rt = 0; rt < 2; rt++) {
    int row = wi * 32 + rt * 16 + r;
    aoff[rt] = row * 32 + (q ^ ((row >> 1) & 3)) * 8;
  }
#pragma unroll
  for (int ct = 0; ct < 8; ct++) {
    int row = wj * 128 + ct * 16 + r;
    boff[ct] = row * 32 + (q ^ ((row >> 1) & 3)) * 8;
  }

  f32x4 acc[2][8];
#pragma unroll
  for (int a = 0; a < 2; a++)
#pragma unroll
    for (int b = 0; b < 8; b++) acc[a][b] = f32x4{0.f, 0.f, 0.f, 0.f};

  // pre-stage ks=0 (m part; no barrier)
  cp16(&As[0 * 4096 + w * 512], mP);
#pragma unroll
  for (int c = 0; c < 2; c++)
    cp16(&Bs[0 * 8192 + c * 4096 + w * 512], WgP + (size_t)(c * 128) * 384);

  for (int ks = 0; ks < 12; ks++) {
    int b = ks & 1;
    if (ks < 11) {
      int nb = b ^ 1;
      int nks = ks + 1;
      const unsigned short* aSrc =
          (nks < 8) ? (mP + nks * 32) : (hP + (nks - 8) * 32);
      cp16(&As[nb * 4096 + w * 512], aSrc);
#pragma unroll
      for (int c = 0; c < 2; c++)
        cp16(&Bs[nb * 8192 + c * 4096 + w * 512],
             WgP + (size_t)(c * 128) * 384 + nks * 32);
      asm volatile("s_waitcnt vmcnt(3)" ::: "memory");
    } else {
      asm volatile("s_waitcnt vmcnt(0)" ::: "memory");
    }
    __builtin_amdgcn_s_barrier();        // B1
    __builtin_amdgcn_sched_barrier(0);
    bfrag af[2];
#pragma unroll
    for (int rt = 0; rt < 2; rt++) af[rt] = *(const bfrag*)&As[b * 4096 + aoff[rt]];
#pragma unroll
    for (int ct = 0; ct < 8; ct++) {
      bfrag bfr = *(const bfrag*)&Bs[b * 8192 + boff[ct]];
#pragma unroll
      for (int rt = 0; rt < 2; rt++)
        acc[rt][ct] =
            __builtin_amdgcn_mfma_f32_16x16x32_bf16(af[rt], bfr, acc[rt][ct], 0, 0, 0);
    }
    __builtin_amdgcn_sched_barrier(0);
    __builtin_amdgcn_s_barrier();        // B2
    __builtin_amdgcn_sched_barrier(0);
  }

  // ---- epilogue phase 1: gates -> pg[il][dl] = pack2((1-z)*n, z) ----
  int rr = r & 3;
  bool s1 = (lane & 1) != 0, s2 = (lane & 2) != 0;
#pragma unroll
  for (int ct = 0; ct < 8; ct++) {
    float bias = biasg[bcol * 256 + wj * 128 + ct * 16 + r];
    int dl = wj * 32 + ct * 4 + (r >> 2);   // local d in [0,64)
#pragma unroll
    for (int rt = 0; rt < 2; rt++) {
      float v0 = acc[rt][ct][0] + bias;
      float v1 = acc[rt][ct][1] + bias;
      float v2 = acc[rt][ct][2] + bias;
      float v3 = acc[rt][ct][3] + bias;
      float t, rcv;
      t = s1 ? v0 : v1; rcv = __shfl_xor(t, 1);
      v0 = s1 ? rcv : v0; v1 = s1 ? v1 : rcv;
      t = s1 ? v2 : v3; rcv = __shfl_xor(t, 1);
      v2 = s1 ? rcv : v2; v3 = s1 ? v3 : rcv;
      t = s2 ? v0 : v2; rcv = __shfl_xor(t, 2);
      v0 = s2 ? rcv : v0; v2 = s2 ? v2 : rcv;
      t = s2 ? v1 : v3; rcv = __shfl_xor(t, 2);
      v1 = s2 ? rcv : v1; v3 = s2 ? v3 : rcv;
      int il = wi * 32 + rt * 16 + q * 4 + rr;
      float rg = sigm_fast(v0), zg = sigm_fast(v1);
      float ng = tanh_fast(v2 + rg * v3);
      pg[il * 66 + dl] = pack2((1.f - zg) * ng, zg);
    }
  }
  __syncthreads();

  // ---- epilogue phase 2: coalesced blend + store ----
#pragma unroll
  for (int half = 0; half < 2; half++) {
    int row = half * 64 + (tid >> 3);
    int c0 = (tid & 7) * 8;
    size_t gbase = (size_t)(i0 + row) * 128 + bcol * 64 + c0;
    bfrag hv8 = *(const bfrag*)&Hc[gbase];
    uint4 p0 = *(const uint4*)&pg[row * 66 + c0];
    uint4 p1 = *(const uint4*)&pg[row * 66 + c0 + 4];
    unsigned pw[8] = {p0.x, p0.y, p0.z, p0.w, p1.x, p1.y, p1.z, p1.w};
    bfrag outv;
#pragma unroll
    for (int e = 0; e < 8; e++) {
      float a = bf2f((unsigned short)(pw[e] & 0xffffu));
      float z = bf2f((unsigned short)(pw[e] >> 16));
      float hold = bf2f((unsigned short)hv8[e]);
      outv[e] = (short)f2bf(a + z * hold);
    }
    *(bfrag*)&Hn[gbase] = outv;
  }
}

// ---------------- readout ----------------
__global__ __launch_bounds__(256) void gate_k(const unsigned short* __restrict__ H,
                                              const float* __restrict__ Wg,
                                              const float* __restrict__ bg,
                                              float* __restrict__ gate) {
  __shared__ float wg[128];
  if (threadIdx.x < 128) wg[threadIdx.x] = Wg[threadIdx.x];
  __syncthreads();
  int g = threadIdx.x >> 4, sub = threadIdx.x & 15;
  int n = blockIdx.x * 16 + g;
  const unsigned short* hr = H + (size_t)n * 128;
  float p = 0.f;
  for (int k = sub; k < 128; k += 16) p += bf2f(hr[k]) * wg[k];
  p += __shfl_xor(p, 1);
  p += __shfl_xor(p, 2);
  p += __shfl_xor(p, 4);
  p += __shfl_xor(p, 8);
  if (sub == 0) gate[n] = sigm(p + bg[0]);
}

// per-graph: gsum[g] = sum gate_n * h_n (fp32), sg[g] = sum gate_n
__global__ __launch_bounds__(256) void gsum_k(const unsigned short* __restrict__ H,
                                              const float* __restrict__ gate,
                                              const int* __restrict__ ptr,
                                              float* __restrict__ gsum,
                                              float* __restrict__ sg) {
  int g = blockIdx.x * 4 + (threadIdx.x >> 6);
  int lane = threadIdx.x & 63;
  int start = ptr[g], end = ptr[g + 1];
  float a0 = 0.f, a1 = 0.f, gs = 0.f;
  for (int n = start; n < end; n++) {
    float gt = gate[n];
    unsigned hv = *(const unsigned*)&H[(size_t)n * 128 + lane * 2];
    a0 += gt * bf2f((unsigned short)(hv & 0xffffu));
    a1 += gt * bf2f((unsigned short)(hv >> 16));
    gs += gt;
  }
  gsum[(size_t)g * 128 + lane * 2] = a0;
  gsum[(size_t)g * 128 + lane * 2 + 1] = a1;
  if (lane == 0) sg[g] = gs;
}

// z[j] = gsum[g] . WcT[:,j] + sg[g]*cvec[j] + bias[j]
__global__ __launch_bounds__(256) void zfinal_k(const float* __restrict__ gsum,
                                                const float* __restrict__ sg,
                                                const float* __restrict__ WcT,
                                                const float* __restrict__ cvec,
                                                const float* __restrict__ bloc,
                                                const float* __restrict__ blv,
                                                float* __restrict__ out) {
  __shared__ float gs[128];
  __shared__ float sgs;
  int g = blockIdx.x;
  int j = threadIdx.x;
  if (j < 128) gs[j] = gsum[(size_t)g * 128 + j];
  if (j == 0) sgs = sg[g];
  __syncthreads();
  float acc = (j < 128 ? bloc[j] : blv[j - 128]) + sgs * cvec[j];
  for (int d = 0; d < 128; d++) acc += gs[d] * WcT[d * 256 + j];
  size_t o = (j < 128) ? ((size_t)g * 128 + j)
                       : ((size_t)GG * 128 + (size_t)g * 128 + (j - 128));
  out[o] = acc;
}

extern "C" void kernel_launch(void* const* d_in, const int* in_sizes, int n_in,
                              void* d_out, int out_size, void* d_ws, size_t ws_size,
                              hipStream_t stream) {
  const int* node_types = (const int*)d_in[0];
  const int* esrc = (const int*)d_in[1];
  const int* edst = (const int*)d_in[2];
  const int* etype = (const int*)d_in[3];
  const int* ptr = (const int*)d_in[4];
  const float* emb = (const float*)d_in[5];
  const float* Wmsg = (const float*)d_in[6];
  const float* bmsg = (const float*)d_in[7];
  const float* Wih = (const float*)d_in[8];
  const float* Whh = (const float*)d_in[9];
  const float* bih = (const float*)d_in[10];
  const float* bhh = (const float*)d_in[11];
  const float* Wg = (const float*)d_in[12];
  const float* bg = (const float*)d_in[13];
  const float* Wn2g = (const float*)d_in[14];
  const float* bn2g = (const float*)d_in[15];
  const float* Wloc = (const float*)d_in[16];
  const float* bloc = (const float*)d_in[17];
  const float* Wlv = (const float*)d_in[18];
  const float* blv = (const float*)d_in[19];
  float* out = (float*)d_out;

  char* ws = (char*)d_ws;
  size_t off = 0;
  unsigned short* s = (unsigned short*)(ws);  // N x 512 bf16; cols [0,256) reused as m
  off += (size_t)NN * 512 * 2;
  unsigned short* H0 = (unsigned short*)(ws + off);  // N x 128 bf16
  off += (size_t)NN * 128 * 2;
  unsigned short* H1 = (unsigned short*)(ws + off);
  off += (size_t)NN * 128 * 2;
  float* cnt = (float*)(ws + off);
  off += (size_t)NN * 4 * 4;
  int* cnti = (int*)(ws + off);
  off += (size_t)NN * 4 * 4;
  int* deg = (int*)(ws + off);
  off += (size_t)NN * 4;
  int* rowptr = (int*)(ws + off);
  off += (size_t)(NN + 64) * 4;
  int* cursor = (int*)(ws + off);
  off += (size_t)NN * 4;
  unsigned* epack = (unsigned*)(ws + off);
  off += (size_t)EE * 4;
  float* gate = (float*)(ws + off);
  off += (size_t)NN * 4;
  float* gsum = (float*)(ws + off);
  off += (size_t)GG * 128 * 4;
  float* sg = (float*)(ws + off);
  off += (size_t)GG * 4;
  float* WcT = (float*)(ws + off);
  off += 128 * 256 * 4;
  float* cvec = (float*)(ws + off);
  off += 256 * 4;
  unsigned short* Wb = (unsigned short*)(ws + off);
  off += 256 * 512 * 2;
  unsigned short* Wgru = (unsigned short*)(ws + off);
  off += 512 * 384 * 2;
  float* biasg = (float*)(ws + off);
  off += 512 * 4;
  // total ~214 MB < 256 MiB ws

  hipMemsetAsync(cnti, 0, (size_t)NN * 16, stream);
  prep_wb<<<512, 256, 0, stream>>>(Wmsg, Wb);
  prep_wgru<<<768, 256, 0, stream>>>(Wih, Whh, Wgru);
  prep_bias<<<2, 256, 0, stream>>>(bih, bhh, biasg);
  compose_k<<<128, 256, 0, stream>>>(Wloc, Wlv, Wn2g, WcT);
  cvec_k<<<1, 256, 0, stream>>>(Wloc, Wlv, bn2g, cvec);
  init_h<<<NN * 128 / 256, 256, 0, stream>>>(node_types, emb, H0);
  cnt4_k<<<EE / 256, 256, 0, stream>>>(edst, etype, cnti);
  degsum_k<<<NN / 256, 256, 0, stream>>>(cnti, deg, cnt);
  scan_k<<<1, 1024, 0, stream>>>(deg, rowptr, cursor);
  fill_k<<<EE / 256, 256, 0, stream>>>(esrc, edst, etype, cursor, epack);

  unsigned short* Hc = H0;
  unsigned short* Hn = H1;
  for (int p = 0; p < NPASS; p++) {
    agg_k<<<NN / 4, 256, 0, stream>>>(rowptr, epack, Hc, s);
    msgemm_k<<<NN / 128, 512, 0, stream>>>(s, cnt, Wb, bmsg);
    grugemm_k<<<NN / 128 * 2, 512, 0, stream>>>(s, Hc, Hn, Wgru, biasg);
    unsigned short* tmp = Hc; Hc = Hn; Hn = tmp;
  }

  gate_k<<<NN / 16, 256, 0, stream>>>(Hc, Wg, bg, gate);
  gsum_k<<<GG / 4, 256, 0, stream>>>(Hc, gate, ptr, gsum, sg);
  zfinal_k<<<GG, 256, 0, stream>>>(gsum, sg, WcT, cvec, bloc, blv, out);
}

// Round 10
// 1070.514 us; speedup vs baseline: 1.1930x; 1.0901x over previous
//
#include <hip/hip_runtime.h>
#include <cstdint>
#include <cstddef>

#define NN 131072
#define EE 524288
#define GG 4096
#define NPASS 4

typedef __attribute__((ext_vector_type(4))) float f32x4;
typedef __attribute__((ext_vector_type(8))) short bfrag;

__device__ __forceinline__ unsigned short f2bf(float f) {
  union { float f; unsigned u; } v; v.f = f;
  unsigned r = v.u + 0x7fffu + ((v.u >> 16) & 1u);
  return (unsigned short)(r >> 16);
}
__device__ __forceinline__ float bf2f(unsigned short h) {
  union { unsigned u; float f; } v; v.u = ((unsigned)h) << 16;
  return v.f;
}
__device__ __forceinline__ unsigned pack2(float x, float y) {
  return (unsigned)f2bf(x) | ((unsigned)f2bf(y) << 16);
}
__device__ __forceinline__ float sigm(float x) { return 1.f / (1.f + __expf(-x)); }
// fast forms (validated R3/R4/R7 at absmax 0.5): v_exp + v_rcp, saturate at +-inf
__device__ __forceinline__ float sigm_fast(float x) {
  return __builtin_amdgcn_rcpf(1.f + __expf(-x));
}
__device__ __forceinline__ float tanh_fast(float x) {
  return 1.f - 2.f * __builtin_amdgcn_rcpf(1.f + __expf(2.f * x));
}

// async global->LDS 16B: LDS dest is wave-uniform base + lane*16
__device__ __forceinline__ void cp16(unsigned short* l, const unsigned short* g) {
  __builtin_amdgcn_global_load_lds(
      (const __attribute__((address_space(1))) unsigned int*)g,
      (__attribute__((address_space(3))) unsigned int*)l, 16, 0, 0);
}

// ---------------- weight prep ----------------
__global__ void prep_wb(const float* __restrict__ Wmsg, unsigned short* __restrict__ Wb) {
  int idx = blockIdx.x * 256 + threadIdx.x;  // 256*512
  if (idx >= 256 * 512) return;
  int m = idx >> 9, k = idx & 511;
  int t = k >> 7, d = k & 127;
  Wb[idx] = f2bf(Wmsg[((size_t)t * 256 + m) * 128 + d]);
}

// Wgru rows interleaved by gate: out-col = 4*d + g, g in {r,z,n,hn}
__global__ void prep_wgru(const float* __restrict__ Wih, const float* __restrict__ Whh,
                          unsigned short* __restrict__ Wgru) {
  int idx = blockIdx.x * 256 + threadIdx.x;  // 512*384
  if (idx >= 512 * 384) return;
  int j = idx / 384, kk = idx % 384;
  float v;
  if (kk < 256) v = (j < 384) ? Wih[j * 256 + kk] : 0.f;
  else          v = (j < 256) ? Whh[j * 128 + (kk - 256)]
                   : ((j >= 384) ? Whh[(j - 128) * 128 + (kk - 256)] : 0.f);
  int g = (j < 128) ? 0 : (j < 256) ? 1 : (j < 384) ? 2 : 3;
  int d = j & 127;
  Wgru[(size_t)(4 * d + g) * 384 + kk] = f2bf(v);
}

__global__ void prep_bias(const float* __restrict__ bih, const float* __restrict__ bhh,
                          float* __restrict__ biasg) {
  int j = blockIdx.x * 256 + threadIdx.x;
  if (j >= 512) return;
  float v;
  if (j < 256) v = bih[j] + bhh[j];
  else if (j < 384) v = bih[j];
  else v = bhh[j - 128];
  int g = (j < 128) ? 0 : (j < 256) ? 1 : (j < 384) ? 2 : 3;
  int d = j & 127;
  biasg[4 * d + g] = v;
}

// WcT[d*256 + j] = sum_k Wx[j][k] * Wn2g[k*128+d], Wx = [Wloc; Wlv] (fp32)
__global__ void compose_k(const float* __restrict__ Wloc, const float* __restrict__ Wlv,
                          const float* __restrict__ Wn2g, float* __restrict__ WcT) {
  int b = blockIdx.x;  // 128 blocks
  int jl = threadIdx.x >> 7, d = threadIdx.x & 127;
  int j = b * 2 + jl;
  const float* wx = (j < 128) ? Wloc + (size_t)j * 512 : Wlv + (size_t)(j - 128) * 512;
  float acc = 0.f;
  for (int k = 0; k < 512; k++) acc += wx[k] * Wn2g[k * 128 + d];
  WcT[d * 256 + j] = acc;
}

__global__ void cvec_k(const float* __restrict__ Wloc, const float* __restrict__ Wlv,
                       const float* __restrict__ bn2g, float* __restrict__ cvec) {
  int j = threadIdx.x;  // 256
  const float* wx = (j < 128) ? Wloc + (size_t)j * 512 : Wlv + (size_t)(j - 128) * 512;
  float a = 0.f;
  for (int k = 0; k < 512; k++) a += wx[k] * bn2g[k];
  cvec[j] = a;
}

// ---------------- init ----------------
__global__ void init_h(const int* __restrict__ nt, const float* __restrict__ emb,
                       unsigned short* __restrict__ H) {
  size_t idx = (size_t)blockIdx.x * 256 + threadIdx.x;  // N*128
  int n = (int)(idx >> 7), d = (int)(idx & 127);
  H[idx] = f2bf(emb[(size_t)nt[n] * 128 + d]);
}

// ---------------- CSR build (once per call) ----------------
__global__ void cnt4_k(const int* __restrict__ edst, const int* __restrict__ etype,
                       int* __restrict__ cnti) {
  int e = blockIdx.x * 256 + threadIdx.x;
  if (e >= EE) return;
  atomicAdd(&cnti[edst[e] * 4 + etype[e]], 1);
}

// deg[n] = sum_t cnti[n*4+t]; cnt (float) copy
__global__ void degsum_k(const int* __restrict__ cnti, int* __restrict__ deg,
                         float* __restrict__ cnt) {
  int n = blockIdx.x * 256 + threadIdx.x;
  if (n >= NN) return;
  int4 c4 = *(const int4*)&cnti[n * 4];
  deg[n] = c4.x + c4.y + c4.z + c4.w;
  float4 f4 = make_float4((float)c4.x, (float)c4.y, (float)c4.z, (float)c4.w);
  *(float4*)&cnt[n * 4] = f4;
}

// R8-kept: int4-vectorized loads/stores (single-block kernel).
__global__ __launch_bounds__(1024) void scan_k(const int* __restrict__ deg,
                                               int* __restrict__ rowptr,
                                               int* __restrict__ cursor) {
  __shared__ int part[1024];
  int t = threadIdx.x;
  int base = t * 128;
  const int4* deg4 = (const int4*)(deg + base);
  int s = 0;
#pragma unroll 8
  for (int i = 0; i < 32; i++) {
    int4 d = deg4[i];
    s += d.x + d.y + d.z + d.w;
  }
  part[t] = s;
  __syncthreads();
  for (int off = 1; off < 1024; off <<= 1) {
    int v = (t >= off) ? part[t - off] : 0;
    __syncthreads();
    part[t] += v;
    __syncthreads();
  }
  int run = part[t] - s;  // exclusive prefix
#pragma unroll 8
  for (int i = 0; i < 32; i++) {
    int4 d = deg4[i];
    int4 rp;
    rp.x = run; run += d.x;
    rp.y = run; run += d.y;
    rp.z = run; run += d.z;
    rp.w = run; run += d.w;
    *(int4*)&rowptr[base + i * 4] = rp;
    *(int4*)&cursor[base + i * 4] = rp;
  }
  if (t == 1023) rowptr[NN] = run;
}

__global__ void fill_k(const int* __restrict__ esrc, const int* __restrict__ edst,
                       const int* __restrict__ etype, int* __restrict__ cursor,
                       unsigned* __restrict__ epack) {
  int e = blockIdx.x * 256 + threadIdx.x;
  if (e >= EE) return;
  int pos = atomicAdd(&cursor[edst[e]], 1);
  epack[pos] = ((unsigned)etype[e] << 17) | (unsigned)esrc[e];
}

// ---------------- per-pass aggregation: s[n, t*128+d] = sum h[src] (bf16 out) ----
// R10 rewrite: paired-row gather + group-of-4 pipeline.
// Lanes 0-31 read edge j's H-row, lanes 32-63 edge j+1's, 8 B/lane (dwordx2):
// one VMEM instruction fetches TWO rows (512 B). A group of 4 edges = 2 such
// loads issued back-to-back (4 edges in flight vs the old 2-deep, half the
// instructions in the serial chain). Lane holds d = (lane&31)*4 + 0..3 per
// type; halves combined by shfl_xor(32) at the end; 8 B/lane stores.
__global__ __launch_bounds__(256) void agg_k(const int* __restrict__ rowptr,
                                             const unsigned* __restrict__ epack,
                                             const unsigned short* __restrict__ H,
                                             unsigned short* __restrict__ s) {
  int n = blockIdx.x * 4 + (threadIdx.x >> 6);
  int lane = threadIdx.x & 63;
  int half = lane >> 5;
  int l31 = lane & 31;
  int beg = rowptr[n], end = rowptr[n + 1];
  const unsigned short* hb = H + l31 * 4;  // +row*128
  float4 acc0 = {0.f, 0.f, 0.f, 0.f}, acc1 = {0.f, 0.f, 0.f, 0.f};
  float4 acc2 = {0.f, 0.f, 0.f, 0.f}, acc3 = {0.f, 0.f, 0.f, 0.f};

#define ACC2(P, HX, HY)                                                        \
  {                                                                            \
    int t_ = (int)((P) >> 17);                                                 \
    float u0 = bf2f((unsigned short)((HX) & 0xffffu));                         \
    float u1 = bf2f((unsigned short)((HX) >> 16));                             \
    float u2 = bf2f((unsigned short)((HY) & 0xffffu));                         \
    float u3 = bf2f((unsigned short)((HY) >> 16));                             \
    if (t_ == 0)      { acc0.x += u0; acc0.y += u1; acc0.z += u2; acc0.w += u3; } \
    else if (t_ == 1) { acc1.x += u0; acc1.y += u1; acc1.z += u2; acc1.w += u3; } \
    else if (t_ == 2) { acc2.x += u0; acc2.y += u1; acc2.z += u2; acc2.w += u3; } \
    else              { acc3.x += u0; acc3.y += u1; acc3.z += u2; acc3.w += u3; } \
  }

  for (int base = beg; base < end; base += 64) {
    int cnt = end - base;
    if (cnt > 64) cnt = 64;
    int mye = base + lane;
    unsigned ep = (mye < end) ? epack[mye] : 0u;  // coalesced pre-load
    for (int jb = 0; jb < cnt; jb += 4) {
      int rem = cnt - jb;
      int jA = jb + half;
      unsigned pA = (unsigned)__shfl((int)ep, jA);
      uint2 hA = make_uint2(0u, 0u);
      if (jA < cnt) hA = *(const uint2*)&hb[(size_t)(pA & 0x1FFFFu) * 128];
      unsigned pB = 0u;
      uint2 hB = make_uint2(0u, 0u);
      if (rem > 2) {
        int jB = jb + 2 + half;
        pB = (unsigned)__shfl((int)ep, jB);
        if (jB < cnt) hB = *(const uint2*)&hb[(size_t)(pB & 0x1FFFFu) * 128];
      }
      ACC2(pA, hA.x, hA.y);
      if (rem > 2) ACC2(pB, hB.x, hB.y);
    }
  }
#undef ACC2

  // combine even/odd-edge halves (lane L <-> L^32 hold the same d-range)
  acc0.x += __shfl_xor(acc0.x, 32); acc0.y += __shfl_xor(acc0.y, 32);
  acc0.z += __shfl_xor(acc0.z, 32); acc0.w += __shfl_xor(acc0.w, 32);
  acc1.x += __shfl_xor(acc1.x, 32); acc1.y += __shfl_xor(acc1.y, 32);
  acc1.z += __shfl_xor(acc1.z, 32); acc1.w += __shfl_xor(acc1.w, 32);
  acc2.x += __shfl_xor(acc2.x, 32); acc2.y += __shfl_xor(acc2.y, 32);
  acc2.z += __shfl_xor(acc2.z, 32); acc2.w += __shfl_xor(acc2.w, 32);
  acc3.x += __shfl_xor(acc3.x, 32); acc3.y += __shfl_xor(acc3.y, 32);
  acc3.z += __shfl_xor(acc3.z, 32); acc3.w += __shfl_xor(acc3.w, 32);

  unsigned short* srow = s + (size_t)n * 512;
  {
    float4 va = half ? acc2 : acc0;
    int t0 = half ? 2 : 0;
    uint2 wv;
    wv.x = pack2(va.x, va.y); wv.y = pack2(va.z, va.w);
    *(uint2*)&srow[t0 * 128 + l31 * 4] = wv;
    float4 vb = half ? acc3 : acc1;
    int t1 = half ? 3 : 1;
    wv.x = pack2(vb.x, vb.y); wv.y = pack2(vb.z, vb.w);
    *(uint2*)&srow[t1 * 128 + l31 * 4] = wv;
  }
}

// ---------------- pass GEMM 1: m = relu(s @ Wb^T + cnt*b_msg) ----------------
// R7/R9-EXACT (measured ~80 us): R2 geometry + R5 counted-vmcnt pipeline +
// scattered epilogue stores.
__global__ __launch_bounds__(512, 4) void msgemm_k(
    unsigned short* __restrict__ s, const float* __restrict__ cnt,
    const unsigned short* __restrict__ Wb, const float* __restrict__ bmsg) {
  __shared__ __align__(16) unsigned short As[2][128 * 32];   // 16 KB
  __shared__ __align__(16) unsigned short Bs[2][256 * 32];   // 32 KB
  int i0 = blockIdx.x * 128;
  int tid = threadIdx.x, lane = tid & 63, w = tid >> 6;
  int wi = w >> 1, wj = w & 1;
  int q = lane >> 4, r = lane & 15;
  int srow = tid >> 2;                                   // staged row (0..127)
  int swcol = ((tid & 3) ^ ((srow >> 1) & 3)) * 8;       // inverse-swizzled col

  const unsigned short* sP = s + (size_t)(i0 + srow) * 512 + swcol;
  const unsigned short* WbP = Wb + (size_t)srow * 512 + swcol;

  // swizzled read offsets (elements)
  int aoff[2], boff[8];
#pragma unroll
  for (int rt = 0; rt < 2; rt++) {
    int row = wi * 32 + rt * 16 + r;
    aoff[rt] = row * 32 + (q ^ ((row >> 1) & 3)) * 8;
  }
#pragma unroll
  for (int ct = 0; ct < 8; ct++) {
    int row = wj * 128 + ct * 16 + r;
    boff[ct] = row * 32 + (q ^ ((row >> 1) & 3)) * 8;
  }

  f32x4 acc[2][8];
#pragma unroll
  for (int a = 0; a < 2; a++)
#pragma unroll
    for (int b = 0; b < 8; b++) acc[a][b] = f32x4{0.f, 0.f, 0.f, 0.f};

  // pre-stage ks=0 (no barrier: first in-loop vmcnt+B1 publishes it)
  cp16(&As[0][w * 512], sP);
#pragma unroll
  for (int c = 0; c < 2; c++)
    cp16(&Bs[0][c * 4096 + w * 512], WbP + (size_t)(c * 128) * 512);

  for (int ks = 0; ks < 16; ks++) {
    int b = ks & 1;
    if (ks < 15) {
      int nb = b ^ 1;
      cp16(&As[nb][w * 512], sP + (ks + 1) * 32);
#pragma unroll
      for (int c = 0; c < 2; c++)
        cp16(&Bs[nb][c * 4096 + w * 512],
             WbP + (size_t)(c * 128) * 512 + (ks + 1) * 32);
      asm volatile("s_waitcnt vmcnt(3)" ::: "memory");  // window ks's loads landed
    } else {
      asm volatile("s_waitcnt vmcnt(0)" ::: "memory");
    }
    __builtin_amdgcn_s_barrier();        // B1: buf b ready for all waves
    __builtin_amdgcn_sched_barrier(0);
    bfrag af[2];
#pragma unroll
    for (int rt = 0; rt < 2; rt++) af[rt] = *(const bfrag*)&As[b][aoff[rt]];
#pragma unroll
    for (int ct = 0; ct < 8; ct++) {
      bfrag bfr = *(const bfrag*)&Bs[b][boff[ct]];
#pragma unroll
      for (int rt = 0; rt < 2; rt++)
        acc[rt][ct] =
            __builtin_amdgcn_mfma_f32_16x16x32_bf16(af[rt], bfr, acc[rt][ct], 0, 0, 0);
    }
    __builtin_amdgcn_sched_barrier(0);
    __builtin_amdgcn_s_barrier();        // B2: all reads of buf b done
    __builtin_amdgcn_sched_barrier(0);
  }

  // epilogue: + cnt*b_msg, relu -> m (= s cols [0,256), stride 512)
#pragma unroll
  for (int ct = 0; ct < 8; ct++) {
    int j = wj * 128 + ct * 16 + r;
    float b0 = bmsg[j], b1 = bmsg[256 + j], b2 = bmsg[512 + j], b3 = bmsg[768 + j];
#pragma unroll
    for (int rt = 0; rt < 2; rt++) {
#pragma unroll
      for (int reg = 0; reg < 4; reg++) {
        int il = wi * 32 + rt * 16 + q * 4 + reg;
        float4 c4 = *(const float4*)&cnt[(size_t)(i0 + il) * 4];
        float v = acc[rt][ct][reg] + c4.x * b0 + c4.y * b1 + c4.z * b2 + c4.w * b3;
        v = v > 0.f ? v : 0.f;
        s[(size_t)(i0 + il) * 512 + j] = f2bf(v);
      }
    }
  }
}

// ---------------- pass GEMM 2: gates = [m | H] @ Wgru^T, GRU epilogue -> Hn ----
// R6 structure (coalesced LDS-staged epilogue) + R7 fast transcendentals.
__global__ __launch_bounds__(512, 4) void grugemm_k(
    const unsigned short* __restrict__ m,   // = s, stride 512, cols [0,256)
    const unsigned short* __restrict__ Hc, unsigned short* __restrict__ Hn,
    const unsigned short* __restrict__ Wgru, const float* __restrict__ biasg) {
  __shared__ __align__(16) unsigned char smem[49152];
  unsigned short* As = (unsigned short*)smem;             // [2][128*32], 16 KB
  unsigned short* Bs = (unsigned short*)(smem + 16384);   // [2][256*32], 32 KB
  unsigned* pg = (unsigned*)smem;                         // epilogue [128][66]
  // grid = 2048; bijective XCD chunking: wg = (bid%8)*256 + bid/8
  int wg = (blockIdx.x & 7) * 256 + (blockIdx.x >> 3);
  int bcol = wg & 1;
  int i0 = (wg >> 1) * 128;
  int tid = threadIdx.x, lane = tid & 63, w = tid >> 6;
  int wi = w >> 1, wj = w & 1;
  int q = lane >> 4, r = lane & 15;
  int srow = tid >> 2;
  int swcol = ((tid & 3) ^ ((srow >> 1) & 3)) * 8;

  const unsigned short* mP = m + (size_t)(i0 + srow) * 512 + swcol;
  const unsigned short* hP = Hc + (size_t)(i0 + srow) * 128 + swcol;
  const unsigned short* WgP = Wgru + (size_t)(bcol * 256 + srow) * 384 + swcol;

  int aoff[2], boff[8];
#pragma unroll
  for (int rt = 0; rt < 2; rt++) {
    int row = wi * 32 + rt * 16 + r;
    aoff[rt] = row * 32 + (q ^ ((row >> 1) & 3)) * 8;
  }
#pragma unroll
  for (int ct = 0; ct < 8; ct++) {
    int row = wj * 128 + ct * 16 + r;
    boff[ct] = row * 32 + (q ^ ((row >> 1) & 3)) * 8;
  }

  f32x4 acc[2][8];
#pragma unroll
  for (int a = 0; a < 2; a++)
#pragma unroll
    for (int b = 0; b < 8; b++) acc[a][b] = f32x4{0.f, 0.f, 0.f, 0.f};

  // pre-stage ks=0 (m part; no barrier)
  cp16(&As[0 * 4096 + w * 512], mP);
#pragma unroll
  for (int c = 0; c < 2; c++)
    cp16(&Bs[0 * 8192 + c * 4096 + w * 512], WgP + (size_t)(c * 128) * 384);

  for (int ks = 0; ks < 12; ks++) {
    int b = ks & 1;
    if (ks < 11) {
      int nb = b ^ 1;
      int nks = ks + 1;
      const unsigned short* aSrc =
          (nks < 8) ? (mP + nks * 32) : (hP + (nks - 8) * 32);
      cp16(&As[nb * 4096 + w * 512], aSrc);
#pragma unroll
      for (int c = 0; c < 2; c++)
        cp16(&Bs[nb * 8192 + c * 4096 + w * 512],
             WgP + (size_t)(c * 128) * 384 + nks * 32);
      asm volatile("s_waitcnt vmcnt(3)" ::: "memory");
    } else {
      asm volatile("s_waitcnt vmcnt(0)" ::: "memory");
    }
    __builtin_amdgcn_s_barrier();        // B1
    __builtin_amdgcn_sched_barrier(0);
    bfrag af[2];
#pragma unroll
    for (int rt = 0; rt < 2; rt++) af[rt] = *(const bfrag*)&As[b * 4096 + aoff[rt]];
#pragma unroll
    for (int ct = 0; ct < 8; ct++) {
      bfrag bfr = *(const bfrag*)&Bs[b * 8192 + boff[ct]];
#pragma unroll
      for (int rt = 0; rt < 2; rt++)
        acc[rt][ct] =
            __builtin_amdgcn_mfma_f32_16x16x32_bf16(af[rt], bfr, acc[rt][ct], 0, 0, 0);
    }
    __builtin_amdgcn_sched_barrier(0);
    __builtin_amdgcn_s_barrier();        // B2
    __builtin_amdgcn_sched_barrier(0);
  }

  // ---- epilogue phase 1: gates -> pg[il][dl] = pack2((1-z)*n, z) ----
  int rr = r & 3;
  bool s1 = (lane & 1) != 0, s2 = (lane & 2) != 0;
#pragma unroll
  for (int ct = 0; ct < 8; ct++) {
    float bias = biasg[bcol * 256 + wj * 128 + ct * 16 + r];
    int dl = wj * 32 + ct * 4 + (r >> 2);   // local d in [0,64)
#pragma unroll
    for (int rt = 0; rt < 2; rt++) {
      float v0 = acc[rt][ct][0] + bias;
      float v1 = acc[rt][ct][1] + bias;
      float v2 = acc[rt][ct][2] + bias;
      float v3 = acc[rt][ct][3] + bias;
      float t, rcv;
      t = s1 ? v0 : v1; rcv = __shfl_xor(t, 1);
      v0 = s1 ? rcv : v0; v1 = s1 ? v1 : rcv;
      t = s1 ? v2 : v3; rcv = __shfl_xor(t, 1);
      v2 = s1 ? rcv : v2; v3 = s1 ? v3 : rcv;
      t = s2 ? v0 : v2; rcv = __shfl_xor(t, 2);
      v0 = s2 ? rcv : v0; v2 = s2 ? v2 : rcv;
      t = s2 ? v1 : v3; rcv = __shfl_xor(t, 2);
      v1 = s2 ? rcv : v1; v3 = s2 ? v3 : rcv;
      int il = wi * 32 + rt * 16 + q * 4 + rr;
      float rg = sigm_fast(v0), zg = sigm_fast(v1);
      float ng = tanh_fast(v2 + rg * v3);
      pg[il * 66 + dl] = pack2((1.f - zg) * ng, zg);
    }
  }
  __syncthreads();

  // ---- epilogue phase 2: coalesced blend + store ----
#pragma unroll
  for (int half = 0; half < 2; half++) {
    int row = half * 64 + (tid >> 3);
    int c0 = (tid & 7) * 8;
    size_t gbase = (size_t)(i0 + row) * 128 + bcol * 64 + c0;
    bfrag hv8 = *(const bfrag*)&Hc[gbase];
    uint4 p0 = *(const uint4*)&pg[row * 66 + c0];
    uint4 p1 = *(const uint4*)&pg[row * 66 + c0 + 4];
    unsigned pw[8] = {p0.x, p0.y, p0.z, p0.w, p1.x, p1.y, p1.z, p1.w};
    bfrag outv;
#pragma unroll
    for (int e = 0; e < 8; e++) {
      float a = bf2f((unsigned short)(pw[e] & 0xffffu));
      float z = bf2f((unsigned short)(pw[e] >> 16));
      float hold = bf2f((unsigned short)hv8[e]);
      outv[e] = (short)f2bf(a + z * hold);
    }
    *(bfrag*)&Hn[gbase] = outv;
  }
}

// ---------------- readout ----------------
__global__ __launch_bounds__(256) void gate_k(const unsigned short* __restrict__ H,
                                              const float* __restrict__ Wg,
                                              const float* __restrict__ bg,
                                              float* __restrict__ gate) {
  __shared__ float wg[128];
  if (threadIdx.x < 128) wg[threadIdx.x] = Wg[threadIdx.x];
  __syncthreads();
  int g = threadIdx.x >> 4, sub = threadIdx.x & 15;
  int n = blockIdx.x * 16 + g;
  const unsigned short* hr = H + (size_t)n * 128;
  float p = 0.f;
  for (int k = sub; k < 128; k += 16) p += bf2f(hr[k]) * wg[k];
  p += __shfl_xor(p, 1);
  p += __shfl_xor(p, 2);
  p += __shfl_xor(p, 4);
  p += __shfl_xor(p, 8);
  if (sub == 0) gate[n] = sigm(p + bg[0]);
}

// per-graph: gsum[g] = sum gate_n * h_n (fp32), sg[g] = sum gate_n
// R10: group-of-4 load pipeline (serial loop was 2-deep latency-bound).
__global__ __launch_bounds__(256) void gsum_k(const unsigned short* __restrict__ H,
                                              const float* __restrict__ gate,
                                              const int* __restrict__ ptr,
                                              float* __restrict__ gsum,
                                              float* __restrict__ sg) {
  int g = blockIdx.x * 4 + (threadIdx.x >> 6);
  int lane = threadIdx.x & 63;
  int start = ptr[g], end = ptr[g + 1];
  float a0 = 0.f, a1 = 0.f, gs = 0.f;
  int n = start;
  for (; n + 4 <= end; n += 4) {
    float g0 = gate[n], g1 = gate[n + 1], g2 = gate[n + 2], g3 = gate[n + 3];
    unsigned v0 = *(const unsigned*)&H[(size_t)n * 128 + lane * 2];
    unsigned v1 = *(const unsigned*)&H[(size_t)(n + 1) * 128 + lane * 2];
    unsigned v2 = *(const unsigned*)&H[(size_t)(n + 2) * 128 + lane * 2];
    unsigned v3 = *(const unsigned*)&H[(size_t)(n + 3) * 128 + lane * 2];
    a0 += g0 * bf2f((unsigned short)(v0 & 0xffffu)) +
          g1 * bf2f((unsigned short)(v1 & 0xffffu)) +
          g2 * bf2f((unsigned short)(v2 & 0xffffu)) +
          g3 * bf2f((unsigned short)(v3 & 0xffffu));
    a1 += g0 * bf2f((unsigned short)(v0 >> 16)) +
          g1 * bf2f((unsigned short)(v1 >> 16)) +
          g2 * bf2f((unsigned short)(v2 >> 16)) +
          g3 * bf2f((unsigned short)(v3 >> 16));
    gs += g0 + g1 + g2 + g3;
  }
  for (; n < end; n++) {
    float gt = gate[n];
    unsigned hv = *(const unsigned*)&H[(size_t)n * 128 + lane * 2];
    a0 += gt * bf2f((unsigned short)(hv & 0xffffu));
    a1 += gt * bf2f((unsigned short)(hv >> 16));
    gs += gt;
  }
  gsum[(size_t)g * 128 + lane * 2] = a0;
  gsum[(size_t)g * 128 + lane * 2 + 1] = a1;
  if (lane == 0) sg[g] = gs;
}

// z[j] = gsum[g] . WcT[:,j] + sg[g]*cvec[j] + bias[j]
__global__ __launch_bounds__(256) void zfinal_k(const float* __restrict__ gsum,
                                                const float* __restrict__ sg,
                                                const float* __restrict__ WcT,
                                                const float* __restrict__ cvec,
                                                const float* __restrict__ bloc,
                                                const float* __restrict__ blv,
                                                float* __restrict__ out) {
  __shared__ float gs[128];
  __shared__ float sgs;
  int g = blockIdx.x;
  int j = threadIdx.x;
  if (j < 128) gs[j] = gsum[(size_t)g * 128 + j];
  if (j == 0) sgs = sg[g];
  __syncthreads();
  float acc = (j < 128 ? bloc[j] : blv[j - 128]) + sgs * cvec[j];
  for (int d = 0; d < 128; d++) acc += gs[d] * WcT[d * 256 + j];
  size_t o = (j < 128) ? ((size_t)g * 128 + j)
                       : ((size_t)GG * 128 + (size_t)g * 128 + (j - 128));
  out[o] = acc;
}

extern "C" void kernel_launch(void* const* d_in, const int* in_sizes, int n_in,
                              void* d_out, int out_size, void* d_ws, size_t ws_size,
                              hipStream_t stream) {
  const int* node_types = (const int*)d_in[0];
  const int* esrc = (const int*)d_in[1];
  const int* edst = (const int*)d_in[2];
  const int* etype = (const int*)d_in[3];
  const int* ptr = (const int*)d_in[4];
  const float* emb = (const float*)d_in[5];
  const float* Wmsg = (const float*)d_in[6];
  const float* bmsg = (const float*)d_in[7];
  const float* Wih = (const float*)d_in[8];
  const float* Whh = (const float*)d_in[9];
  const float* bih = (const float*)d_in[10];
  const float* bhh = (const float*)d_in[11];
  const float* Wg = (const float*)d_in[12];
  const float* bg = (const float*)d_in[13];
  const float* Wn2g = (const float*)d_in[14];
  const float* bn2g = (const float*)d_in[15];
  const float* Wloc = (const float*)d_in[16];
  const float* bloc = (const float*)d_in[17];
  const float* Wlv = (const float*)d_in[18];
  const float* blv = (const float*)d_in[19];
  float* out = (float*)d_out;

  char* ws = (char*)d_ws;
  size_t off = 0;
  unsigned short* s = (unsigned short*)(ws);  // N x 512 bf16; cols [0,256) reused as m
  off += (size_t)NN * 512 * 2;
  unsigned short* H0 = (unsigned short*)(ws + off);  // N x 128 bf16
  off += (size_t)NN * 128 * 2;
  unsigned short* H1 = (unsigned short*)(ws + off);
  off += (size_t)NN * 128 * 2;
  float* cnt = (float*)(ws + off);
  off += (size_t)NN * 4 * 4;
  int* cnti = (int*)(ws + off);
  off += (size_t)NN * 4 * 4;
  int* deg = (int*)(ws + off);
  off += (size_t)NN * 4;
  int* rowptr = (int*)(ws + off);
  off += (size_t)(NN + 64) * 4;
  int* cursor = (int*)(ws + off);
  off += (size_t)NN * 4;
  unsigned* epack = (unsigned*)(ws + off);
  off += (size_t)EE * 4;
  float* gate = (float*)(ws + off);
  off += (size_t)NN * 4;
  float* gsum = (float*)(ws + off);
  off += (size_t)GG * 128 * 4;
  float* sg = (float*)(ws + off);
  off += (size_t)GG * 4;
  float* WcT = (float*)(ws + off);
  off += 128 * 256 * 4;
  float* cvec = (float*)(ws + off);
  off += 256 * 4;
  unsigned short* Wb = (unsigned short*)(ws + off);
  off += 256 * 512 * 2;
  unsigned short* Wgru = (unsigned short*)(ws + off);
  off += 512 * 384 * 2;
  float* biasg = (float*)(ws + off);
  off += 512 * 4;
  // total ~214 MB < 256 MiB ws

  hipMemsetAsync(cnti, 0, (size_t)NN * 16, stream);
  prep_wb<<<512, 256, 0, stream>>>(Wmsg, Wb);
  prep_wgru<<<768, 256, 0, stream>>>(Wih, Whh, Wgru);
  prep_bias<<<2, 256, 0, stream>>>(bih, bhh, biasg);
  compose_k<<<128, 256, 0, stream>>>(Wloc, Wlv, Wn2g, WcT);
  cvec_k<<<1, 256, 0, stream>>>(Wloc, Wlv, bn2g, cvec);
  init_h<<<NN * 128 / 256, 256, 0, stream>>>(node_types, emb, H0);
  cnt4_k<<<EE / 256, 256, 0, stream>>>(edst, etype, cnti);
  degsum_k<<<NN / 256, 256, 0, stream>>>(cnti, deg, cnt);
  scan_k<<<1, 1024, 0, stream>>>(deg, rowptr, cursor);
  fill_k<<<EE / 256, 256, 0, stream>>>(esrc, edst, etype, cursor, epack);

  unsigned short* Hc = H0;
  unsigned short* Hn = H1;
  for (int p = 0; p < NPASS; p++) {
    agg_k<<<NN / 4, 256, 0, stream>>>(rowptr, epack, Hc, s);
    msgemm_k<<<NN / 128, 512, 0, stream>>>(s, cnt, Wb, bmsg);
    grugemm_k<<<NN / 128 * 2, 512, 0, stream>>>(s, Hc, Hn, Wgru, biasg);
    unsigned short* tmp = Hc; Hc = Hn; Hn = tmp;
  }

  gate_k<<<NN / 16, 256, 0, stream>>>(Hc, Wg, bg, gate);
  gsum_k<<<GG / 4, 256, 0, stream>>>(Hc, gate, ptr, gsum, sg);
  zfinal_k<<<GG, 256, 0, stream>>>(gsum, sg, WcT, cvec, bloc, blv, out);
}